// Round 6
// baseline (617.044 us; speedup 1.0000x reference)
//
#include <hip/hip_runtime.h>
#include <stdint.h>

// Shapes fixed by the problem: B=4,H=16 -> BH=64; S=1024; D=64.
// d_ws layout (needs 28 MB):
//   [0,8M)    Qb  bf16 [bh][s][d]  (pre-scaled by 1/8)
//   [8M,16M)  Kb  bf16 [bh][s][d]
//   [16M,24M) Vt  bf16 [bh][d][s]  (V transposed)
//   [24M,28M) Mb  u8   [b][q][k]   (mask canonicalized to bytes)

#define S_LEN 1024
#define D_DIM 64
#define QT 16
#define NEG_FILL (-1000000000.0f)
#define LOG2E 1.44269504088896340736f

typedef __bf16 bf16x8 __attribute__((ext_vector_type(8)));
typedef float f32x4 __attribute__((ext_vector_type(4)));
typedef unsigned short u16x4 __attribute__((ext_vector_type(4)));

__device__ __forceinline__ unsigned short f2bf(float x) {
    unsigned u = __builtin_bit_cast(unsigned, x);
    u += 0x7fffu + ((u >> 16) & 1u);
    return (unsigned short)(u >> 16);
}
__device__ __forceinline__ float bf2f(unsigned short b) {
    return __builtin_bit_cast(float, (unsigned)b << 16);
}

// Batched asm loads (phase 2 only): an asm def cannot be sunk, so a burst
// of 32 stays fully in flight until ONE vmcnt(0) drain. No counted
// per-step waits anywhere (round-5 lesson: rigid WAITV ladders regress).
__device__ __forceinline__ float gloadf_nt(const void* p) {   // sim: stream-once -> nt
    float d;
    asm volatile("global_load_dword %0, %1, off nt" : "=v"(d) : "v"(p) : "memory");
    return d;
}
__device__ __forceinline__ unsigned gloadub(const void* p) {  // mask: L2-hot, cached
    unsigned d;
    asm volatile("global_load_ubyte %0, %1, off" : "=v"(d) : "v"(p) : "memory");
    return d;
}
#define WAITV0 do { \
    asm volatile("s_waitcnt vmcnt(0)" ::: "memory"); \
    __builtin_amdgcn_sched_barrier(0); } while (0)

// Swizzled LDS addressing for the 16x1024 u16 prob block: 2048 B rows,
// XOR a 16B-granular row-dependent swizzle (32 KB exactly, no pad).
__device__ __forceinline__ unsigned short* sptr(unsigned short* s, int row, int col) {
    return (unsigned short*)((char*)s + row * 2048 + ((col * 2) ^ ((row & 7) << 4)));
}

// ---- prep: q,k -> bf16 (q pre-scaled) + mask -> bytes, fused -------------
__global__ void prep_qkm(const float* __restrict__ q, const float* __restrict__ k,
                         const void* __restrict__ mraw,
                         unsigned short* __restrict__ Qb, unsigned short* __restrict__ Kb,
                         unsigned char* __restrict__ Mb)
{
    const int t = threadIdx.x;
    const int i = blockIdx.x * 256 + t;           // float4 / uchar4 index, 1,048,576 total
    f32x4 q4 = ((const f32x4*)q)[i];
    f32x4 k4 = ((const f32x4*)k)[i];
    u16x4 qo, ko;
#pragma unroll
    for (int j = 0; j < 4; ++j) {
        qo[j] = f2bf(q4[j] * 0.125f);
        ko[j] = f2bf(k4[j]);
    }
    ((u16x4*)Qb)[i] = qo;
    ((u16x4*)Kb)[i] = ko;

    // mask format detect (cheap, L2-broadcast) then canonicalize 4 elements
    __shared__ int s_not_int, s_not_f32;
    if (t == 0) { s_not_int = 0; s_not_f32 = 0; }
    __syncthreads();
    const unsigned* wdd = (const unsigned*)mraw;
    int ni = 0, nf = 0;
    for (int j = t; j < 1024; j += 256) {
        unsigned x = wdd[j];
        if (x > 1u) ni = 1;
        if (x != 0u && x != 0x3f800000u) nf = 1;
    }
    if (ni) s_not_int = 1;
    if (nf) s_not_f32 = 1;
    __syncthreads();
    const int fmt = (s_not_int == 0) ? 0 : ((s_not_f32 == 0) ? 1 : 2);
    uchar4 o;
    if (fmt == 0) {        // int32 0/1
        int4 x = ((const int4*)mraw)[i];
        o.x = x.x ? 1 : 0; o.y = x.y ? 1 : 0; o.z = x.z ? 1 : 0; o.w = x.w ? 1 : 0;
    } else if (fmt == 1) { // fp32 0.0/1.0
        float4 x = ((const float4*)mraw)[i];
        o.x = (x.x != 0.f) ? 1 : 0; o.y = (x.y != 0.f) ? 1 : 0;
        o.z = (x.z != 0.f) ? 1 : 0; o.w = (x.w != 0.f) ? 1 : 0;
    } else {               // bool bytes
        uchar4 x = ((const uchar4*)mraw)[i];
        o.x = x.x ? 1 : 0; o.y = x.y ? 1 : 0; o.z = x.z ? 1 : 0; o.w = x.w ? 1 : 0;
    }
    ((uchar4*)Mb)[i] = o;
}

// ---- prep: V -> V^T bf16 (64x64 tiles through LDS) -----------------------
__global__ void prep_vt(const float* __restrict__ v, unsigned short* __restrict__ Vt)
{
    __shared__ unsigned short sT[64 * 72];
    const int bh = blockIdx.x >> 4;
    const int st = blockIdx.x & 15;
    const int t = threadIdx.x;
    const float* vb = v + (size_t)(bh * S_LEN + st * 64) * D_DIM;
#pragma unroll
    for (int p = 0; p < 4; ++p) {
        int lin = p * 256 + t;
        int r = lin >> 4;
        int c = lin & 15;
        f32x4 x = ((const f32x4*)(vb + r * D_DIM))[c];
        unsigned short* dst = &sT[r * 72 + c * 4];
#pragma unroll
        for (int j = 0; j < 4; ++j) dst[j] = f2bf(x[j]);
    }
    __syncthreads();
    unsigned short* ob = Vt + (size_t)bh * D_DIM * S_LEN + st * 64;
#pragma unroll
    for (int p = 0; p < 4; ++p) {
        int lin = p * 256 + t;
        int d = lin >> 4;
        int s4 = (lin & 15) * 4;
        u16x4 o;
#pragma unroll
        for (int j = 0; j < 4; ++j) o[j] = sT[(s4 + j) * 72 + d];
        *(u16x4*)&ob[d * S_LEN + s4] = o;
    }
}

// ---- main ----------------------------------------------------------------
// Round-4 structure at round-3 occupancy:
//   1. QK^T, scores stay in f32 REGISTERS (C-layout acc[16]); plain
//      compiler-scheduled K loads (L2-hot). NO LDS, NO barrier.
//   2. sim + mask gathered directly in C-layout (4 B/1 B per lane) via
//      BATCHED asm loads: 4 chunks x {32 loads in flight -> one vmcnt(0)
//      -> consume}. nt on sim (stream-once). All 128 B lines consumed
//      within one block -> HBM traffic unchanged vs row-major.
//   3. C-layout softmax: 16-lane shfl reduce + 512 B LDS cross-wave
//      combine (2 barriers).
//   4. probs bf16 -> 32 KB LDS park (3rd barrier), PV = verified plain
//      two-chain loop, out stores, then coalesced attn epilogue from LDS.
// LDS 33 KB -> 4 blocks/CU (16 waves), vs round-4's 67 KB / 2 blocks.
__global__ __launch_bounds__(256, 4)
void attn_main(const float* __restrict__ simg_, const unsigned short* __restrict__ Qb,
               const unsigned short* __restrict__ Kb, const unsigned short* __restrict__ Vtb,
               const unsigned char* __restrict__ Mb, float* __restrict__ out,
               float* __restrict__ attn)
{
    __shared__ __align__(16) unsigned short sS[QT * S_LEN];   // 32768 B prob park
    __shared__ __align__(16) float cmb[128];                  // 64 max + 64 sum

    const int blk = ((blockIdx.x & 7) << 9) | (blockIdx.x >> 3);  // XCD-contiguous (-55 MB FETCH)
    const int bh = blk >> 6;
    const int qt = blk & 63;
    const int b = bh >> 4;
    const int t = threadIdx.x;
    const int w = t >> 6;
    const int lane = t & 63;
    const int quad = lane >> 4;
    const int l15 = lane & 15;
    const int n0 = w * 16;

    const unsigned short* Qg = Qb + (size_t)(bh * S_LEN + qt * QT) * D_DIM;
    const unsigned short* Kg = Kb + (size_t)bh * S_LEN * D_DIM;
    const unsigned short* Vg = Vtb + (size_t)bh * D_DIM * S_LEN;
    const float* simg = simg_ + ((size_t)(bh * S_LEN + qt * QT)) * S_LEN;
    const unsigned char* mg = Mb + ((size_t)(b * S_LEN + qt * QT)) * S_LEN;
    float* attng = attn + ((size_t)(bh * S_LEN + qt * QT)) * S_LEN;

    // ---- 1. QK^T: acc[kt][r] = score(row=quad*4+r, col=kt*64+n0+l15), f32.
    const bf16x8 av0 = *(const bf16x8*)&Qg[l15 * D_DIM + quad * 8];
    const bf16x8 av1 = *(const bf16x8*)&Qg[l15 * D_DIM + 32 + quad * 8];
    f32x4 acc[16];
#pragma unroll
    for (int kt = 0; kt < 16; ++kt) {
        const unsigned short* kp = &Kg[(size_t)(kt * 64 + n0 + l15) * D_DIM + quad * 8];
        bf16x8 kv0 = *(const bf16x8*)kp;
        bf16x8 kv1 = *(const bf16x8*)(kp + 32);
        f32x4 a = {0.f, 0.f, 0.f, 0.f};
        a = __builtin_amdgcn_mfma_f32_16x16x32_bf16(av0, kv0, a, 0, 0, 0);
        a = __builtin_amdgcn_mfma_f32_16x16x32_bf16(av1, kv1, a, 0, 0, 0);
        acc[kt] = a;
    }

    // ---- 2. sim += / mask, C-layout direct gathers in 4 batched chunks.
    //         32 asm loads in flight per chunk (16 sim f32 + 16 mask u8),
    //         one drain, consume. Peak VGPR ~116 < 128 cap (no spill).
#pragma unroll
    for (int C = 0; C < 16; C += 4) {
        float sv_[4][4];
        unsigned mk_[4][4];
#pragma unroll
        for (int kk = 0; kk < 4; ++kk)
#pragma unroll
            for (int r = 0; r < 4; ++r) {
                const size_t off = (size_t)(quad * 4 + r) * S_LEN + (C + kk) * 64 + n0 + l15;
                sv_[kk][r] = gloadf_nt(simg + off);
                mk_[kk][r] = gloadub(mg + off);
            }
        WAITV0;
#pragma unroll
        for (int kk = 0; kk < 4; ++kk)
#pragma unroll
            for (int r = 0; r < 4; ++r)
                acc[C + kk][r] = mk_[kk][r] ? NEG_FILL : (acc[C + kk][r] + sv_[kk][r]);
    }

    // ---- 3a. row max: lane kt-reduce -> 16-lane-group shfl -> LDS combine.
    float* cmbMax = cmb;
    float* cmbSum = cmb + 64;
    float pm[4];
#pragma unroll
    for (int r = 0; r < 4; ++r) {
        float m = acc[0][r];
#pragma unroll
        for (int kt = 1; kt < 16; ++kt) m = fmaxf(m, acc[kt][r]);
#pragma unroll
        for (int off = 1; off <= 8; off <<= 1)
            m = fmaxf(m, __shfl_xor(m, off, 64));
        pm[r] = m;
    }
    if (l15 == 0) {
        f32x4 v = {pm[0], pm[1], pm[2], pm[3]};
        *(f32x4*)&cmbMax[w * 16 + quad * 4] = v;
    }
    __syncthreads();   // b1
    float rM[4];
#pragma unroll
    for (int r = 0; r < 4; ++r) {
        const int row = quad * 4 + r;
        rM[r] = fmaxf(fmaxf(cmbMax[row], cmbMax[16 + row]),
                      fmaxf(cmbMax[32 + row], cmbMax[48 + row]));
    }

    // ---- 3b. exp + row sum (same combine pattern).
    float ps[4] = {0.f, 0.f, 0.f, 0.f};
#pragma unroll
    for (int kt = 0; kt < 16; ++kt)
#pragma unroll
        for (int r = 0; r < 4; ++r) {
            float e = __builtin_amdgcn_exp2f((acc[kt][r] - rM[r]) * LOG2E);
            acc[kt][r] = e;
            ps[r] += e;
        }
#pragma unroll
    for (int r = 0; r < 4; ++r)
#pragma unroll
        for (int off = 1; off <= 8; off <<= 1)
            ps[r] += __shfl_xor(ps[r], off, 64);
    if (l15 == 0) {
        f32x4 v = {ps[0], ps[1], ps[2], ps[3]};
        *(f32x4*)&cmbSum[w * 16 + quad * 4] = v;
    }
    __syncthreads();   // b2
    float rinv[4];
#pragma unroll
    for (int r = 0; r < 4; ++r) {
        const int row = quad * 4 + r;
        rinv[r] = 1.0f / ((cmbSum[row] + cmbSum[16 + row]) +
                          (cmbSum[32 + row] + cmbSum[48 + row]));
    }

    // ---- 4. probs bf16 -> LDS park (acc dead after this: frees pressure).
#pragma unroll
    for (int kt = 0; kt < 16; ++kt)
#pragma unroll
        for (int r = 0; r < 4; ++r)
            *sptr(sS, quad * 4 + r, kt * 64 + n0 + l15) = f2bf(acc[kt][r] * rinv[r]);
    __syncthreads();   // b3

    // ---- 5. PV = P @ V. A from LDS park, B direct from Vt (L2-hot).
    //         Plain compiler-scheduled loads (verified-good form).
    const int d0 = w * 16;
    f32x4 oa0 = {0.f, 0.f, 0.f, 0.f}, oa1 = {0.f, 0.f, 0.f, 0.f};
#pragma unroll
    for (int kt = 0; kt < 16; kt += 2) {
        const unsigned short* vp0 = &Vg[(size_t)(d0 + l15) * S_LEN + kt * 64 + quad * 8];
        bf16x8 x0 = *(const bf16x8*)vp0;
        bf16x8 x1 = *(const bf16x8*)(vp0 + 32);
        bf16x8 y0 = *(const bf16x8*)(vp0 + 64);
        bf16x8 y1 = *(const bf16x8*)(vp0 + 96);
        bf16x8 pa0 = *(const bf16x8*)sptr(sS, l15, kt * 64 + quad * 8);
        bf16x8 pa1 = *(const bf16x8*)sptr(sS, l15, kt * 64 + 32 + quad * 8);
        bf16x8 pb0 = *(const bf16x8*)sptr(sS, l15, kt * 64 + 64 + quad * 8);
        bf16x8 pb1 = *(const bf16x8*)sptr(sS, l15, kt * 64 + 96 + quad * 8);
        oa0 = __builtin_amdgcn_mfma_f32_16x16x32_bf16(pa0, x0, oa0, 0, 0, 0);
        oa0 = __builtin_amdgcn_mfma_f32_16x16x32_bf16(pa1, x1, oa0, 0, 0, 0);
        oa1 = __builtin_amdgcn_mfma_f32_16x16x32_bf16(pb0, y0, oa1, 0, 0, 0);
        oa1 = __builtin_amdgcn_mfma_f32_16x16x32_bf16(pb1, y1, oa1, 0, 0, 0);
    }
    f32x4 oacc = oa0 + oa1;

    float* og = out + ((size_t)(bh * S_LEN + qt * QT)) * D_DIM;
#pragma unroll
    for (int r = 0; r < 4; ++r)
        __builtin_nontemporal_store(oacc[r], &og[(quad * 4 + r) * D_DIM + d0 + l15]);

    // ---- 6. attn epilogue: coalesced f32x4 stores from parked bf16 probs
    //         (store-acks never block anything; bf16 rounding verified
    //         within margin in round 5, absmax 0.0156).
#pragma unroll
    for (int rr = 0; rr < 4; ++rr) {
        const int row = w * 4 + rr;
#pragma unroll
        for (int j = 0; j < 4; ++j) {
            const int col = j * 256 + lane * 4;
            u16x4 x = *(const u16x4*)sptr(sS, row, col);
            f32x4 p = { bf2f(x[0]), bf2f(x[1]), bf2f(x[2]), bf2f(x[3]) };
            __builtin_nontemporal_store(p, (f32x4*)&attng[(size_t)row * S_LEN + col]);
        }
    }
}

extern "C" void kernel_launch(void* const* d_in, const int* in_sizes, int n_in,
                              void* d_out, int out_size, void* d_ws, size_t ws_size,
                              hipStream_t stream)
{
    const float* q = (const float*)d_in[0];
    const float* k = (const float*)d_in[1];
    const float* v = (const float*)d_in[2];
    const float* sim = (const float*)d_in[3];
    const void* mask = d_in[4];
    float* out = (float*)d_out;
    float* attn = out + (size_t)4 * 16 * 1024 * 64;   // output first, then attn

    char* ws = (char*)d_ws;                           // needs 28 MB
    unsigned short* Qb = (unsigned short*)(ws + (size_t)0);
    unsigned short* Kb = (unsigned short*)(ws + ((size_t)8 << 20));
    unsigned short* Vt = (unsigned short*)(ws + ((size_t)16 << 20));
    unsigned char*  Mb = (unsigned char*)(ws + ((size_t)24 << 20));

    prep_qkm<<<4096, 256, 0, stream>>>(q, k, mask, Qb, Kb, Mb);
    prep_vt<<<1024, 256, 0, stream>>>(v, Vt);
    attn_main<<<4096, 256, 0, stream>>>(sim, Qb, Kb, Vt, Mb, out, attn);
}